// Round 9
// baseline (2487.913 us; speedup 1.0000x reference)
//
#include <hip/hip_runtime.h>
#include <cstdint>
#include <cstddef>

// ---------------------------------------------------------------------------
// TLSTM: B=64, S=512, I=256, H=256
// R9 = R8 with ONE change: XCD-local partner placement. R8's counters showed
// FETCH_SIZE 159MB (vs 43MB in R7) -> the per-step h/c exchange was crossing
// XCDs (partners had consecutive bids -> round-robin onto different XCDs and
// every gather missed local L2). Now G = bid&7 (<4, else exit), q = bid>>3:
// all 16 partner blocks of a group are congruent mod 8 -> same XCD -> tags +
// 16KB gather served by the local 4MB L2.
// Grid 128 (64 real blocks + 64 immediate-exit dummies).
// ---------------------------------------------------------------------------

#define B_   64
#define S_   512
#define H_   256
#define BSH_ ((size_t)B_ * S_ * H_)  // 8388608

typedef _Float16 f16;
typedef _Float16 f16x8 __attribute__((ext_vector_type(8)));
typedef short    s16x8 __attribute__((ext_vector_type(8)));
typedef float    f32x4 __attribute__((ext_vector_type(4)));

static __device__ __forceinline__ unsigned short f32_to_bf16(float f) {
    union { float f; uint32_t u; } v; v.f = f;
    uint32_t u = v.u;
    u += 0x7fffu + ((u >> 16) & 1u);   // RTNE
    return (unsigned short)(u >> 16);
}

static __device__ __forceinline__ float sigm(float z) {
    return 1.0f / (1.0f + __expf(-z));
}
static __device__ __forceinline__ float tanh_fast(float z) {
    float e = __expf(-2.0f * fabsf(z));
    float t = (1.0f - e) / (1.0f + e);
    return z >= 0.0f ? t : -t;
}

// ---------------------------------------------------------------------------
// prep: W4 (bf16, [1024][256]) + fused bias4 (Wg_b + b_g + Ug_b)
// ---------------------------------------------------------------------------
__global__ void prep_w4(const float* __restrict__ Wi, const float* __restrict__ Wf,
                        const float* __restrict__ Wo, const float* __restrict__ Wc,
                        const float* __restrict__ Wib, const float* __restrict__ Wfb,
                        const float* __restrict__ Wob, const float* __restrict__ Wcb,
                        const float* __restrict__ Uib, const float* __restrict__ Ufb,
                        const float* __restrict__ Uob, const float* __restrict__ Ucb,
                        const float* __restrict__ bi,  const float* __restrict__ bf_,
                        const float* __restrict__ bo,  const float* __restrict__ bc,
                        unsigned short* __restrict__ W4, float* __restrict__ bias4) {
    const int n = blockIdx.x;        // 0..1023
    const int k = threadIdx.x;       // 0..255
    const int g = n >> 8, o = n & 255;
    const float* W = (g == 0) ? Wi : (g == 1) ? Wf : (g == 2) ? Wo : Wc;
    W4[n * 256 + k] = f32_to_bf16(W[o * 256 + k]);
    if (k == 0) {
        const float* wb = (g == 0) ? Wib : (g == 1) ? Wfb : (g == 2) ? Wob : Wcb;
        const float* ub = (g == 0) ? Uib : (g == 1) ? Ufb : (g == 2) ? Uob : Ucb;
        const float* sb = (g == 0) ? bi  : (g == 1) ? bf_ : (g == 2) ? bo  : bc;
        bias4[n] = wb[o] + ub[o] + sb[o];
    }
}

// ---------------------------------------------------------------------------
// prep: weight B-fragments, fragment-linear:
// wfg[ ((q*5+g)*8+ks)*64 + l ] (uint4) = f16x8 of
//   U_g[ 16q + (l&15) ][ 32ks + (l>>4)*8 .. +8 ]
// ---------------------------------------------------------------------------
__global__ void prep_wfrag(const float* __restrict__ Ui, const float* __restrict__ Uf,
                           const float* __restrict__ Uo, const float* __restrict__ Uc,
                           const float* __restrict__ Wd, uint4* __restrict__ wfg) {
    const int id = blockIdx.x * 256 + threadIdx.x;   // 0..40959
    const int l  = id & 63;
    const int ks = (id >> 6) & 7;
    const int qg = id >> 9;          // 0..79
    const int q  = qg / 5;
    const int g  = qg - q * 5;
    const float* U = (g == 0) ? Ui : (g == 1) ? Uf : (g == 2) ? Uo : (g == 3) ? Uc : Wd;
    const int row = 16 * q + (l & 15);
    const int k0  = 32 * ks + (l >> 4) * 8;
    const float* src = U + (size_t)row * 256 + k0;
    union { f16 h[8]; uint4 v; } pk;
    #pragma unroll
    for (int i = 0; i < 8; ++i) pk.h[i] = (f16)src[i];
    wfg[id] = pk.v;
}

// prep: Tm1[m] = 1/log(ts+2.7183) - 1
__global__ void prep_T(const float* __restrict__ tsp, float* __restrict__ Tm1) {
    const int i = blockIdx.x * 256 + threadIdx.x;   // 0..32767
    Tm1[i] = 1.0f / logf(tsp[i] + 2.7183f) - 1.0f;
}

// zero the sync tags (runs every launch; graph replays it)
__global__ void prep_zero(unsigned int* __restrict__ tags) {
    tags[blockIdx.x * 256 + threadIdx.x] = 0u;
}

// ---------------------------------------------------------------------------
// Projection GEMM: Xbuf[m][j][g] f16 (gate-interleaved; recur reads uint2).
// ---------------------------------------------------------------------------
__global__ __launch_bounds__(256) void proj_gemm(const float* __restrict__ X,
        const unsigned short* __restrict__ W4, const float* __restrict__ bias4,
        f16* __restrict__ Xbuf) {
    __shared__ __align__(16) unsigned short a_s[64 * 40];
    __shared__ __align__(16) unsigned short b_s[64 * 40];
    const int bid = blockIdx.x;
    const int m0 = (bid >> 4) * 64;
    const int n0 = (bid & 15) * 64;
    const int tid  = threadIdx.x;
    const int lane = tid & 63;
    const int w    = tid >> 6;
    const int srow = tid >> 2;
    const int scol = (tid & 3) * 8;
    const int r  = lane & 15;
    const int kg = lane >> 4;

    f32x4 acc[4] = {{0,0,0,0},{0,0,0,0},{0,0,0,0},{0,0,0,0}};

    for (int kt = 0; kt < 8; ++kt) {
        const int k0 = kt * 32;
        float4 av0 = *reinterpret_cast<const float4*>(X + (size_t)(m0 + srow) * 256 + k0 + scol);
        float4 av1 = *reinterpret_cast<const float4*>(X + (size_t)(m0 + srow) * 256 + k0 + scol + 4);
        union { unsigned short us[8]; uint4 v; } pk;
        pk.us[0] = f32_to_bf16(av0.x); pk.us[1] = f32_to_bf16(av0.y);
        pk.us[2] = f32_to_bf16(av0.z); pk.us[3] = f32_to_bf16(av0.w);
        pk.us[4] = f32_to_bf16(av1.x); pk.us[5] = f32_to_bf16(av1.y);
        pk.us[6] = f32_to_bf16(av1.z); pk.us[7] = f32_to_bf16(av1.w);
        *reinterpret_cast<uint4*>(a_s + srow * 40 + scol) = pk.v;
        uint4 bv = *reinterpret_cast<const uint4*>(W4 + (size_t)(n0 + srow) * 256 + k0 + scol);
        *reinterpret_cast<uint4*>(b_s + srow * 40 + scol) = bv;
        __syncthreads();

        s16x8 af = *reinterpret_cast<const s16x8*>(a_s + (w * 16 + r) * 40 + kg * 8);
        #pragma unroll
        for (int nt = 0; nt < 4; ++nt) {
            s16x8 bfr = *reinterpret_cast<const s16x8*>(b_s + (nt * 16 + r) * 40 + kg * 8);
            acc[nt] = __builtin_amdgcn_mfma_f32_16x16x32_bf16(af, bfr, acc[nt], 0, 0, 0);
        }
        __syncthreads();
    }
    #pragma unroll
    for (int nt = 0; nt < 4; ++nt) {
        const int n = n0 + nt * 16 + r;
        const int gidx = n >> 8, jj = n & 255;
        const float bn = bias4[n];
        #pragma unroll
        for (int reg = 0; reg < 4; ++reg) {
            const int m = m0 + w * 16 + kg * 4 + reg;
            Xbuf[((size_t)m * 256 + jj) * 4 + gidx] = (f16)(acc[nt][reg] + bn);
        }
    }
}

// ---------------------------------------------------------------------------
// Recurrence. Grid 128; real blocks: G = bid&7 (<4), q = bid>>3 (0..15).
// All partners of group G share bid%8 == G -> same XCD.
// ---------------------------------------------------------------------------
__global__ __launch_bounds__(320) void recur(
        const uint4* __restrict__ wfg, const f16* __restrict__ Xbuf,
        const float* __restrict__ Wdb, const float* __restrict__ bdv,
        const float* __restrict__ Tm1,
        uint4* __restrict__ hxf, uint4* __restrict__ cxf,
        unsigned int* __restrict__ tags, float* __restrict__ out) {
    extern __shared__ __align__(16) char smemraw[];
    uint4* wfr  = (uint4*)smemraw;            // 2560 units (40KB)
    uint4* hfr  = wfr + 2560;                 // 512 units  (8KB)
    uint4* cfr  = hfr + 512;                  // 512 units  (8KB)
    float* pre  = (float*)(cfr + 512);        // [16][89] f32 (5696B)
    f16*   stgh = (f16*)(pre + 16 * 89);      // 256 f16 (512B)
    f16*   stgc = stgh + 256;                 // 256 f16
    float* obh  = (float*)(stgc + 256);       // [8][256] f32 (8KB)
    float* obc  = obh + 2048;                 // [8][256] f32

    const int tid = threadIdx.x;
    const int bid = blockIdx.x;
    const int G = bid & 7;           // batch group (XCD id under round-robin)
    const int q = bid >> 3;          // row shard 0..15
    if (G >= 4) return;              // dummy block (keeps partners same-XCD)
    const int g = tid >> 6;          // wave = matrix 0..4
    const int l = tid & 63;

    // ---- stage weight frags (global fragment-linear -> LDS linear) ----
    {
        const uint4* src = wfg + (size_t)q * 2560;
        #pragma unroll
        for (int i = 0; i < 8; ++i) wfr[tid + i * 320] = src[tid + i * 320];
    }
    // ---- zero h/c frags ----
    if (tid < 256) {
        uint4 z = {0, 0, 0, 0};
        hfr[tid] = z; hfr[tid + 256] = z;
        cfr[tid] = z; cfr[tid + 256] = z;
    }
    // gate-thread state
    const int gb = tid >> 4;         // batch 0..15  (tid<256)
    const int jl = tid & 15;         // local j
    const int j  = 16 * q + jl;      // hidden index
    float cj = 0.0f, bD = 0.0f;
    if (tid < 256) bD = Wdb[j] + bdv[j];
    __syncthreads();

    const uint4* afr = (g == 4) ? cfr : hfr;
    uint4* hxb = hxf + (size_t)G * 1024;      // [par][512]
    uint4* cxb = cxf + (size_t)G * 1024;
    unsigned int* tg = tags + (size_t)G * 512; // [par][16 slots x 16dw]

    for (int s = 0; s < 512; ++s) {
        const int par = s & 1;

        // prefetch gate inputs (consumed after barrier 1)
        uint2 xv = {0, 0};
        float tm1 = 0.f;
        size_t m = 0;
        if (tid < 256) {
            m = (size_t)(16 * G + gb) * 512 + s;
            xv  = *reinterpret_cast<const uint2*>(Xbuf + (m * 256 + j) * 4);
            tm1 = Tm1[m];
        }

        // ---- MFMA matvec: pre[batch][g*16 + jl] ----
        f32x4 acc = {0.f, 0.f, 0.f, 0.f};
        #pragma unroll
        for (int ks = 0; ks < 8; ++ks) {
            f16x8 a  = __builtin_bit_cast(f16x8, afr[ks * 64 + l]);
            f16x8 bb = __builtin_bit_cast(f16x8, wfr[(g * 8 + ks) * 64 + l]);
            acc = __builtin_amdgcn_mfma_f32_16x16x32_f16(a, bb, acc, 0, 0, 0);
        }
        {
            const int mb = (l >> 4) * 4;          // batch base (D rows)
            const int nn = g * 16 + (l & 15);     // local row (D col)
            #pragma unroll
            for (int reg = 0; reg < 4; ++reg)
                pre[(mb + reg) * 89 + nn] = acc[reg];
        }
        __syncthreads();                          // B1: preacts ready

        // ---- gates (threads 0..255, 1 (batch,j) pair each) ----
        if (tid < 256) {
            const float* pb = pre + gb * 89;
            const f16* xp = reinterpret_cast<const f16*>(&xv);
            float CST  = tanh_fast(pb[64 + jl] + bD);
            float cdec = cj + tm1 * CST;
            float ig = sigm((float)xp[0] + pb[jl]);
            float fg = sigm((float)xp[1] + pb[16 + jl]);
            float og = sigm((float)xp[2] + pb[32 + jl]);
            float Cn = tanh_fast((float)xp[3] + pb[48 + jl]);
            cj = fg * cdec + ig * Cn;
            float hn = og * tanh_fast(cj);
            stgh[tid] = (f16)hn;
            stgc[tid] = (f16)cj;
            obh[(s & 7) * 256 + tid] = hn;
            obc[(s & 7) * 256 + tid] = cj;
        }
        __syncthreads();                          // B2: staging/obuf ready

        if (s != 511) {
            // ---- publish own h/c chunk in FRAGMENT layout (wave 0) ----
            if (tid < 64) {
                const int b   = tid & 15;
                const int kgo = (tid >> 4) & 1;
                const bool isC = tid >= 32;
                uint4 v = *reinterpret_cast<const uint4*>(
                    (isC ? stgc : stgh) + b * 16 + kgo * 8);
                const int u = (q >> 1) * 64 + ((q & 1) * 2 + kgo) * 16 + b;
                (isC ? cxb : hxb)[par * 512 + u] = v;
            }
            if (tid == 0)
                __hip_atomic_store(tg + par * 256 + q * 16, (unsigned)(s + 1),
                                   __ATOMIC_RELEASE, __HIP_MEMORY_SCOPE_AGENT);
        }
        // ---- output flush every 8 steps (overlaps partner wait) ----
        if ((s & 7) == 7 && tid < 256) {
            #pragma unroll
            for (int sf = 0; sf < 8; ++sf) {
                const size_t mm = (size_t)(16 * G + gb) * 512 + (s - 7 + sf);
                const size_t oi = mm * 256 + j;
                float hv = obh[sf * 256 + tid];
                float cv = obc[sf * 256 + tid];
                out[oi] = hv; out[BSH_ + oi] = hv; out[2 * BSH_ + oi] = cv;
            }
        }
        if (s != 511) {
            // ---- poll 16 partners ----
            if (tid < 16) {
                while (__hip_atomic_load(tg + par * 256 + tid * 16,
                                         __ATOMIC_ACQUIRE, __HIP_MEMORY_SCOPE_AGENT)
                       < (unsigned)(s + 1))
                    __builtin_amdgcn_s_sleep(1);
            }
            __syncthreads();                      // B3: all chunks published
            // ---- gather full h/c frags (linear: conflict-free) ----
            if (tid < 256) {
                hfr[tid]       = hxb[par * 512 + tid];
                hfr[tid + 256] = hxb[par * 512 + tid + 256];
                cfr[tid]       = cxb[par * 512 + tid];
                cfr[tid + 256] = cxb[par * 512 + tid + 256];
            }
        }
        __syncthreads();                          // B4: frags ready / flush done
    }
}

// ---------------------------------------------------------------------------
extern "C" void kernel_launch(void* const* d_in, const int* in_sizes, int n_in,
                              void* d_out, int out_size, void* d_ws, size_t ws_size,
                              hipStream_t stream) {
    const float* inputs = (const float*)d_in[0];
    const float* tsp    = (const float*)d_in[1];
    const float* Wi_w = (const float*)d_in[2],  * Wi_b = (const float*)d_in[3];
    const float* Ui_w = (const float*)d_in[4],  * Ui_b = (const float*)d_in[5];
    const float* Wf_w = (const float*)d_in[6],  * Wf_b = (const float*)d_in[7];
    const float* Uf_w = (const float*)d_in[8],  * Uf_b = (const float*)d_in[9];
    const float* Wo_w = (const float*)d_in[10], * Wo_b = (const float*)d_in[11];
    const float* Uo_w = (const float*)d_in[12], * Uo_b = (const float*)d_in[13];
    const float* Wc_w = (const float*)d_in[14], * Wc_b = (const float*)d_in[15];
    const float* Uc_w = (const float*)d_in[16], * Uc_b = (const float*)d_in[17];
    const float* Wd_w = (const float*)d_in[18], * Wd_b = (const float*)d_in[19];
    const float* bi = (const float*)d_in[20], * bf_ = (const float*)d_in[21];
    const float* bo = (const float*)d_in[22], * bc  = (const float*)d_in[23];
    const float* bd = (const float*)d_in[24];

    // workspace layout (16B-aligned):
    //   Xbuf  f16   [32768][256][4]  67,108,864 B @ 0
    //   W4    bf16  [1024][256]         524,288 B @ 67,108,864
    //   bias4 f32   [1024]                4,096 B @ 67,633,152
    //   wfg   uint4 [40960]             655,360 B @ 67,637,248
    //   hxf   uint4 [4][2][512]          65,536 B @ 68,292,608
    //   cxf   uint4 [4][2][512]          65,536 B @ 68,358,144
    //   Tm1   f32   [32768]             131,072 B @ 68,423,680
    //   tags  u32   [4][2][16][16]        8,192 B @ 68,554,752
    char* ws = (char*)d_ws;
    f16*            Xbuf  = (f16*)ws;
    unsigned short* W4    = (unsigned short*)(ws + 67108864);
    float*          bias4 = (float*)(ws + 67633152);
    uint4*          wfg   = (uint4*)(ws + 67637248);
    uint4*          hxf   = (uint4*)(ws + 68292608);
    uint4*          cxf   = (uint4*)(ws + 68358144);
    float*          Tm1   = (float*)(ws + 68423680);
    unsigned int*   tags  = (unsigned int*)(ws + 68554752);

    prep_w4<<<1024, 256, 0, stream>>>(Wi_w, Wf_w, Wo_w, Wc_w,
                                      Wi_b, Wf_b, Wo_b, Wc_b,
                                      Ui_b, Uf_b, Uo_b, Uc_b,
                                      bi, bf_, bo, bc, W4, bias4);
    prep_wfrag<<<160, 256, 0, stream>>>(Ui_w, Uf_w, Uo_w, Uc_w, Wd_w, wfg);
    prep_T<<<128, 256, 0, stream>>>(tsp, Tm1);
    prep_zero<<<8, 256, 0, stream>>>(tags);
    proj_gemm<<<8192, 256, 0, stream>>>(inputs, W4, bias4, Xbuf);

    const size_t lds_bytes = 2560 * 16 + 1024 * 16 + 16 * 89 * 4
                           + 512 * 2 + 2 * 2048 * 4;   // 80,448 B
    recur<<<128, 320, lds_bytes, stream>>>(wfg, Xbuf, Wd_b, bd, Tm1,
                                           hxf, cxf, tags, (float*)d_out);
}

// Round 12
// 1272.325 us; speedup vs baseline: 1.9554x; 1.9554x over previous
//
#include <hip/hip_runtime.h>
#include <cstdint>
#include <cstddef>

// ---------------------------------------------------------------------------
// TLSTM: B=64, S=512, I=256, H=256
// R12 = R11 with the exchange coherence point moved from the per-XCD L2 (sc0
// only — WRONG when the bid%8->XCD heuristic misses, which R11 proved happens:
// absmax 0.245 with the spin-cap firing) to the die-level Infinity Cache via
// per-access sc0+sc1 flags (device scope, RCCL-style flag exchange). This is
// XCD-mapping-INDEPENDENT, yet still avoids the wholesale L2 inv/writeback
// that agent-scope compiler atomics emit per acquire/release (R9: 17+ per
// block-step = the theorized 4.7us/step stall).
// ---------------------------------------------------------------------------

#define B_   64
#define S_   512
#define H_   256
#define BSH_ ((size_t)B_ * S_ * H_)  // 8388608

typedef _Float16 f16;
typedef _Float16 f16x8 __attribute__((ext_vector_type(8)));
typedef short    s16x8 __attribute__((ext_vector_type(8)));
typedef float    f32x4 __attribute__((ext_vector_type(4)));
typedef unsigned int u32x4 __attribute__((ext_vector_type(4)));

static __device__ __forceinline__ unsigned short f32_to_bf16(float f) {
    union { float f; uint32_t u; } v; v.f = f;
    uint32_t u = v.u;
    u += 0x7fffu + ((u >> 16) & 1u);   // RTNE
    return (unsigned short)(u >> 16);
}

static __device__ __forceinline__ float sigm(float z) {
    return 1.0f / (1.0f + __expf(-z));
}
static __device__ __forceinline__ float tanh_fast(float z) {
    float e = __expf(-2.0f * fabsf(z));
    float t = (1.0f - e) / (1.0f + e);
    return z >= 0.0f ? t : -t;
}

// ---------------------------------------------------------------------------
// prep: W4 (bf16, [1024][256]) + fused bias4 (Wg_b + b_g + Ug_b)
// ---------------------------------------------------------------------------
__global__ void prep_w4(const float* __restrict__ Wi, const float* __restrict__ Wf,
                        const float* __restrict__ Wo, const float* __restrict__ Wc,
                        const float* __restrict__ Wib, const float* __restrict__ Wfb,
                        const float* __restrict__ Wob, const float* __restrict__ Wcb,
                        const float* __restrict__ Uib, const float* __restrict__ Ufb,
                        const float* __restrict__ Uob, const float* __restrict__ Ucb,
                        const float* __restrict__ bi,  const float* __restrict__ bf_,
                        const float* __restrict__ bo,  const float* __restrict__ bc,
                        unsigned short* __restrict__ W4, float* __restrict__ bias4) {
    const int n = blockIdx.x;        // 0..1023
    const int k = threadIdx.x;       // 0..255
    const int g = n >> 8, o = n & 255;
    const float* W = (g == 0) ? Wi : (g == 1) ? Wf : (g == 2) ? Wo : Wc;
    W4[n * 256 + k] = f32_to_bf16(W[o * 256 + k]);
    if (k == 0) {
        const float* wb = (g == 0) ? Wib : (g == 1) ? Wfb : (g == 2) ? Wob : Wcb;
        const float* ub = (g == 0) ? Uib : (g == 1) ? Ufb : (g == 2) ? Uob : Ucb;
        const float* sb = (g == 0) ? bi  : (g == 1) ? bf_ : (g == 2) ? bo  : bc;
        bias4[n] = wb[o] + ub[o] + sb[o];
    }
}

// ---------------------------------------------------------------------------
// prep: weight B-fragments, fragment-linear:
// wfg[ ((q*5+g)*8+ks)*64 + l ] (uint4) = f16x8 of
//   U_g[ 16q + (l&15) ][ 32ks + (l>>4)*8 .. +8 ]
// ---------------------------------------------------------------------------
__global__ void prep_wfrag(const float* __restrict__ Ui, const float* __restrict__ Uf,
                           const float* __restrict__ Uo, const float* __restrict__ Uc,
                           const float* __restrict__ Wd, uint4* __restrict__ wfg) {
    const int id = blockIdx.x * 256 + threadIdx.x;   // 0..40959
    const int l  = id & 63;
    const int ks = (id >> 6) & 7;
    const int qg = id >> 9;          // 0..79
    const int q  = qg / 5;
    const int g  = qg - q * 5;
    const float* U = (g == 0) ? Ui : (g == 1) ? Uf : (g == 2) ? Uo : (g == 3) ? Uc : Wd;
    const int row = 16 * q + (l & 15);
    const int k0  = 32 * ks + (l >> 4) * 8;
    const float* src = U + (size_t)row * 256 + k0;
    union { f16 h[8]; uint4 v; } pk;
    #pragma unroll
    for (int i = 0; i < 8; ++i) pk.h[i] = (f16)src[i];
    wfg[id] = pk.v;
}

// prep: Tm1[m] = 1/log(ts+2.7183) - 1
__global__ void prep_T(const float* __restrict__ tsp, float* __restrict__ Tm1) {
    const int i = blockIdx.x * 256 + threadIdx.x;   // 0..32767
    Tm1[i] = 1.0f / logf(tsp[i] + 2.7183f) - 1.0f;
}

// zero the sync tags (runs every launch; graph replays it)
__global__ void prep_zero(unsigned int* __restrict__ tags) {
    tags[blockIdx.x * 256 + threadIdx.x] = 0u;
}

// ---------------------------------------------------------------------------
// Projection GEMM: Xbuf[m][j][g] f16 (gate-interleaved; recur reads uint2).
// ---------------------------------------------------------------------------
__global__ __launch_bounds__(256) void proj_gemm(const float* __restrict__ X,
        const unsigned short* __restrict__ W4, const float* __restrict__ bias4,
        f16* __restrict__ Xbuf) {
    __shared__ __align__(16) unsigned short a_s[64 * 40];
    __shared__ __align__(16) unsigned short b_s[64 * 40];
    const int bid = blockIdx.x;
    const int m0 = (bid >> 4) * 64;
    const int n0 = (bid & 15) * 64;
    const int tid  = threadIdx.x;
    const int lane = tid & 63;
    const int w    = tid >> 6;
    const int srow = tid >> 2;
    const int scol = (tid & 3) * 8;
    const int r  = lane & 15;
    const int kg = lane >> 4;

    f32x4 acc[4] = {{0,0,0,0},{0,0,0,0},{0,0,0,0},{0,0,0,0}};

    for (int kt = 0; kt < 8; ++kt) {
        const int k0 = kt * 32;
        float4 av0 = *reinterpret_cast<const float4*>(X + (size_t)(m0 + srow) * 256 + k0 + scol);
        float4 av1 = *reinterpret_cast<const float4*>(X + (size_t)(m0 + srow) * 256 + k0 + scol + 4);
        union { unsigned short us[8]; uint4 v; } pk;
        pk.us[0] = f32_to_bf16(av0.x); pk.us[1] = f32_to_bf16(av0.y);
        pk.us[2] = f32_to_bf16(av0.z); pk.us[3] = f32_to_bf16(av0.w);
        pk.us[4] = f32_to_bf16(av1.x); pk.us[5] = f32_to_bf16(av1.y);
        pk.us[6] = f32_to_bf16(av1.z); pk.us[7] = f32_to_bf16(av1.w);
        *reinterpret_cast<uint4*>(a_s + srow * 40 + scol) = pk.v;
        uint4 bv = *reinterpret_cast<const uint4*>(W4 + (size_t)(n0 + srow) * 256 + k0 + scol);
        *reinterpret_cast<uint4*>(b_s + srow * 40 + scol) = bv;
        __syncthreads();

        s16x8 af = *reinterpret_cast<const s16x8*>(a_s + (w * 16 + r) * 40 + kg * 8);
        #pragma unroll
        for (int nt = 0; nt < 4; ++nt) {
            s16x8 bfr = *reinterpret_cast<const s16x8*>(b_s + (nt * 16 + r) * 40 + kg * 8);
            acc[nt] = __builtin_amdgcn_mfma_f32_16x16x32_bf16(af, bfr, acc[nt], 0, 0, 0);
        }
        __syncthreads();
    }
    #pragma unroll
    for (int nt = 0; nt < 4; ++nt) {
        const int n = n0 + nt * 16 + r;
        const int gidx = n >> 8, jj = n & 255;
        const float bn = bias4[n];
        #pragma unroll
        for (int reg = 0; reg < 4; ++reg) {
            const int m = m0 + w * 16 + kg * 4 + reg;
            Xbuf[((size_t)m * 256 + jj) * 4 + gidx] = (f16)(acc[nt][reg] + bn);
        }
    }
}

// ---------------------------------------------------------------------------
// Recurrence. Grid 128; real blocks: G = bid&7 (<4), q = bid>>3 (0..15).
// The %8 grouping is now PERF-ONLY (shorter IC paths); correctness rests on
// device-scope sc0 sc1 accesses through the Infinity Cache.
// ---------------------------------------------------------------------------
__global__ __launch_bounds__(320) void recur(
        const uint4* __restrict__ wfg, const f16* __restrict__ Xbuf,
        const float* __restrict__ Wdb, const float* __restrict__ bdv,
        const float* __restrict__ Tm1,
        uint4* __restrict__ hxf, uint4* __restrict__ cxf,
        unsigned int* __restrict__ tags, float* __restrict__ out) {
    extern __shared__ __align__(16) char smemraw[];
    uint4* wfr  = (uint4*)smemraw;            // 2560 units (40KB)
    uint4* hfr  = wfr + 2560;                 // 512 units  (8KB)
    uint4* cfr  = hfr + 512;                  // 512 units  (8KB)
    float* pre  = (float*)(cfr + 512);        // [16][89] f32 (5696B)
    f16*   stgh = (f16*)(pre + 16 * 89);      // 256 f16 (512B)
    f16*   stgc = stgh + 256;                 // 256 f16
    float* obh  = (float*)(stgc + 256);       // [8][256] f32 (8KB)
    float* obc  = obh + 2048;                 // [8][256] f32

    const int tid = threadIdx.x;
    const int bid = blockIdx.x;
    const int G = bid & 7;           // batch group (perf-only XCD affinity)
    const int q = bid >> 3;          // row shard 0..15
    if (G >= 4) return;              // dummy block
    const int g = tid >> 6;          // wave = matrix 0..4
    const int l = tid & 63;

    // ---- stage weight frags (global fragment-linear -> LDS linear) ----
    {
        const uint4* src = wfg + (size_t)q * 2560;
        #pragma unroll
        for (int i = 0; i < 8; ++i) wfr[tid + i * 320] = src[tid + i * 320];
    }
    // ---- zero h/c frags ----
    if (tid < 256) {
        uint4 z = {0, 0, 0, 0};
        hfr[tid] = z; hfr[tid + 256] = z;
        cfr[tid] = z; cfr[tid + 256] = z;
    }
    // gate-thread state
    const int gb = tid >> 4;         // batch 0..15  (tid<256)
    const int jl = tid & 15;         // local j
    const int j  = 16 * q + jl;      // hidden index
    float cj = 0.0f, bD = 0.0f;
    if (tid < 256) bD = Wdb[j] + bdv[j];
    __syncthreads();

    const uint4* afr = (g == 4) ? cfr : hfr;
    uint4* hxb = hxf + (size_t)G * 1024;      // [par][512]
    uint4* cxb = cxf + (size_t)G * 1024;
    unsigned int* tg = tags + (size_t)G * 512; // [par][16 slots x 16dw]

    for (int s = 0; s < 512; ++s) {
        const int par = s & 1;

        // prefetch gate inputs (consumed after barrier 1)
        uint2 xv = {0, 0};
        float tm1 = 0.f;
        size_t m = 0;
        if (tid < 256) {
            m = (size_t)(16 * G + gb) * 512 + s;
            xv  = *reinterpret_cast<const uint2*>(Xbuf + (m * 256 + j) * 4);
            tm1 = Tm1[m];
        }

        // ---- MFMA matvec: pre[batch][g*16 + jl] ----
        f32x4 acc = {0.f, 0.f, 0.f, 0.f};
        #pragma unroll
        for (int ks = 0; ks < 8; ++ks) {
            f16x8 a  = __builtin_bit_cast(f16x8, afr[ks * 64 + l]);
            f16x8 bb = __builtin_bit_cast(f16x8, wfr[(g * 8 + ks) * 64 + l]);
            acc = __builtin_amdgcn_mfma_f32_16x16x32_f16(a, bb, acc, 0, 0, 0);
        }
        {
            const int mb = (l >> 4) * 4;          // batch base (D rows)
            const int nn = g * 16 + (l & 15);     // local row (D col)
            #pragma unroll
            for (int reg = 0; reg < 4; ++reg)
                pre[(mb + reg) * 89 + nn] = acc[reg];
        }
        __syncthreads();                          // B1: preacts ready

        // ---- gates (threads 0..255, 1 (batch,j) pair each) ----
        if (tid < 256) {
            const float* pb = pre + gb * 89;
            const f16* xp = reinterpret_cast<const f16*>(&xv);
            float CST  = tanh_fast(pb[64 + jl] + bD);
            float cdec = cj + tm1 * CST;
            float ig = sigm((float)xp[0] + pb[jl]);
            float fg = sigm((float)xp[1] + pb[16 + jl]);
            float og = sigm((float)xp[2] + pb[32 + jl]);
            float Cn = tanh_fast((float)xp[3] + pb[48 + jl]);
            cj = fg * cdec + ig * Cn;
            float hn = og * tanh_fast(cj);
            stgh[tid] = (f16)hn;
            stgc[tid] = (f16)cj;
            obh[(s & 7) * 256 + tid] = hn;
            obc[(s & 7) * 256 + tid] = cj;
        }
        __syncthreads();                          // B2: staging/obuf ready

        if (s != 511) {
            // ---- publish own h/c chunk, device-coherent via IC (sc0 sc1) ----
            if (tid < 64) {
                const int b   = tid & 15;
                const int kgo = (tid >> 4) & 1;
                const bool isC = tid >= 32;
                u32x4 v = __builtin_bit_cast(u32x4, *reinterpret_cast<const uint4*>(
                    (isC ? stgc : stgh) + b * 16 + kgo * 8));
                const int u = (q >> 1) * 64 + ((q & 1) * 2 + kgo) * 16 + b;
                uint4* pp = (isC ? cxb : hxb) + par * 512 + u;
                asm volatile("global_store_dwordx4 %0, %1, off sc0 sc1"
                             :: "v"(pp), "v"(v) : "memory");
                // publish stores acked at the coherence point -> release tag
                asm volatile("s_waitcnt vmcnt(0)" ::: "memory");
                if (tid == 0) {
                    unsigned int* tp = tg + par * 256 + q * 16;
                    unsigned tagv = (unsigned)(s + 1);
                    asm volatile("global_store_dword %0, %1, off sc0 sc1"
                                 :: "v"(tp), "v"(tagv) : "memory");
                }
            }
        }
        // ---- output flush every 8 steps (overlaps partner wait) ----
        if ((s & 7) == 7 && tid < 256) {
            #pragma unroll
            for (int sf = 0; sf < 8; ++sf) {
                const size_t mm = (size_t)(16 * G + gb) * 512 + (s - 7 + sf);
                const size_t oi = mm * 256 + j;
                float hv = obh[sf * 256 + tid];
                float cv = obc[sf * 256 + tid];
                out[oi] = hv; out[BSH_ + oi] = hv; out[2 * BSH_ + oi] = cv;
            }
        }
        if (s != 511) {
            // ---- poll 16 partners, device-coherent loads (sc0 sc1) ----
            if (tid < 16) {
                const unsigned int* tp = tg + par * 256 + tid * 16;
                unsigned v;
                int spins = 0;
                for (;;) {
                    asm volatile("global_load_dword %0, %1, off sc0 sc1\n\t"
                                 "s_waitcnt vmcnt(0)"
                                 : "=v"(v) : "v"(tp) : "memory");
                    if (v >= (unsigned)(s + 1)) break;
                    if (++spins > (1 << 22)) break;   // timeout insurance only
                    __builtin_amdgcn_s_sleep(1);
                }
            }
            __syncthreads();                      // B3: all chunks published
            // ---- gather full h/c frags from IC (sc0 sc1, pipelined) ----
            if (tid < 256) {
                const uint4* p0 = hxb + par * 512 + tid;
                const uint4* p1 = hxb + par * 512 + tid + 256;
                const uint4* p2 = cxb + par * 512 + tid;
                const uint4* p3 = cxb + par * 512 + tid + 256;
                u32x4 va, vb, vc, vd;
                asm volatile(
                    "global_load_dwordx4 %0, %4, off sc0 sc1\n\t"
                    "global_load_dwordx4 %1, %5, off sc0 sc1\n\t"
                    "global_load_dwordx4 %2, %6, off sc0 sc1\n\t"
                    "global_load_dwordx4 %3, %7, off sc0 sc1\n\t"
                    "s_waitcnt vmcnt(0)"
                    : "=&v"(va), "=&v"(vb), "=&v"(vc), "=&v"(vd)
                    : "v"(p0), "v"(p1), "v"(p2), "v"(p3)
                    : "memory");
                hfr[tid]       = __builtin_bit_cast(uint4, va);
                hfr[tid + 256] = __builtin_bit_cast(uint4, vb);
                cfr[tid]       = __builtin_bit_cast(uint4, vc);
                cfr[tid + 256] = __builtin_bit_cast(uint4, vd);
            }
        }
        __syncthreads();                          // B4: frags ready / flush done
    }
}

// ---------------------------------------------------------------------------
extern "C" void kernel_launch(void* const* d_in, const int* in_sizes, int n_in,
                              void* d_out, int out_size, void* d_ws, size_t ws_size,
                              hipStream_t stream) {
    const float* inputs = (const float*)d_in[0];
    const float* tsp    = (const float*)d_in[1];
    const float* Wi_w = (const float*)d_in[2],  * Wi_b = (const float*)d_in[3];
    const float* Ui_w = (const float*)d_in[4],  * Ui_b = (const float*)d_in[5];
    const float* Wf_w = (const float*)d_in[6],  * Wf_b = (const float*)d_in[7];
    const float* Uf_w = (const float*)d_in[8],  * Uf_b = (const float*)d_in[9];
    const float* Wo_w = (const float*)d_in[10], * Wo_b = (const float*)d_in[11];
    const float* Uo_w = (const float*)d_in[12], * Uo_b = (const float*)d_in[13];
    const float* Wc_w = (const float*)d_in[14], * Wc_b = (const float*)d_in[15];
    const float* Uc_w = (const float*)d_in[16], * Uc_b = (const float*)d_in[17];
    const float* Wd_w = (const float*)d_in[18], * Wd_b = (const float*)d_in[19];
    const float* bi = (const float*)d_in[20], * bf_ = (const float*)d_in[21];
    const float* bo = (const float*)d_in[22], * bc  = (const float*)d_in[23];
    const float* bd = (const float*)d_in[24];

    // workspace layout (16B-aligned):
    //   Xbuf  f16   [32768][256][4]  67,108,864 B @ 0
    //   W4    bf16  [1024][256]         524,288 B @ 67,108,864
    //   bias4 f32   [1024]                4,096 B @ 67,633,152
    //   wfg   uint4 [40960]             655,360 B @ 67,637,248
    //   hxf   uint4 [4][2][512]          65,536 B @ 68,292,608
    //   cxf   uint4 [4][2][512]          65,536 B @ 68,358,144
    //   Tm1   f32   [32768]             131,072 B @ 68,423,680
    //   tags  u32   [4][2][16][16]        8,192 B @ 68,554,752
    char* ws = (char*)d_ws;
    f16*            Xbuf  = (f16*)ws;
    unsigned short* W4    = (unsigned short*)(ws + 67108864);
    float*          bias4 = (float*)(ws + 67633152);
    uint4*          wfg   = (uint4*)(ws + 67637248);
    uint4*          hxf   = (uint4*)(ws + 68292608);
    uint4*          cxf   = (uint4*)(ws + 68358144);
    float*          Tm1   = (float*)(ws + 68423680);
    unsigned int*   tags  = (unsigned int*)(ws + 68554752);

    prep_w4<<<1024, 256, 0, stream>>>(Wi_w, Wf_w, Wo_w, Wc_w,
                                      Wi_b, Wf_b, Wo_b, Wc_b,
                                      Ui_b, Uf_b, Uo_b, Uc_b,
                                      bi, bf_, bo, bc, W4, bias4);
    prep_wfrag<<<160, 256, 0, stream>>>(Ui_w, Uf_w, Uo_w, Uc_w, Wd_w, wfg);
    prep_T<<<128, 256, 0, stream>>>(tsp, Tm1);
    prep_zero<<<8, 256, 0, stream>>>(tags);
    proj_gemm<<<8192, 256, 0, stream>>>(inputs, W4, bias4, Xbuf);

    const size_t lds_bytes = 2560 * 16 + 1024 * 16 + 16 * 89 * 4
                           + 512 * 2 + 2 * 2048 * 4;   // 80,448 B
    recur<<<128, 320, lds_bytes, stream>>>(wfg, Xbuf, Wd_b, bd, Tm1,
                                           hxf, cxf, tags, (float*)d_out);
}